// Round 3
// baseline (64.462 us; speedup 1.0000x reference)
//
#include <hip/hip_runtime.h>
#include <math.h>

#define NB   2
#define L0   4800
#define L1   4800
#define H1C  60
#define W1C  80
#define ROWS 8
#define RPB  (L0 / ROWS)          // 600 row-groups per batch
#define NBLK (NB * RPB)           // 1200 blocks
#define CH   1200                 // points per LDS chunk
#define CH4  (CH / 2)             // float4 per chunk = 600
// partials layout: k in [0,12): {Sm,Sl2,Ssl2,Ss,Sv,Ssq} x {word-mask, byte-mask}

__global__ __launch_bounds__(256) void s2ld_fused(
    const float* __restrict__ w_pt0,    // [NB][L0][2]
    const float* __restrict__ pt1,      // [NB][L1][2]
    const void*  __restrict__ maskp,    // [NB][L0], format unknown (word or byte)
    const float* __restrict__ score0,   // [NB][L0]
    const float* __restrict__ score1,   // [NB][L1]
    const float* __restrict__ scale0,   // [NB][2]
    const float* __restrict__ scale1,   // [NB][2]
    float*       __restrict__ partials, // [12][NBLK]
    unsigned int* __restrict__ counter,
    float*       __restrict__ out)      // [3]
{
    __shared__ float4 sA[CH4];          // 9600 B
    __shared__ float4 sB[CH4];          // 9600 B
    __shared__ float  redd[ROWS * 4];
    __shared__ int    redj[ROWS * 4];
    __shared__ float  fin[6 * 4];
    __shared__ int    slast;
    __shared__ unsigned int sbad;

    const int tid  = threadIdx.x;
    const int blk  = blockIdx.x;
    const int n    = blk / RPB;
    const int i0   = (blk % RPB) * ROWS;
    const int lane = tid & 63;
    const int wv   = tid >> 6;

    const float4* p1 = (const float4*)(pt1 + (size_t)n * L1 * 2);  // 2400 float4
    const float2* p0 = (const float2*)(w_pt0 + ((size_t)n * L0 + i0) * 2);

    // query points for this block (block-uniform). CRITICAL: these arrays are
    // only ever indexed by compile-time constants (fully unrolled loops) so
    // they stay in registers. Round-2 indexed px[tid] -> scratch -> 5x slow.
    float px[ROWS], py[ROWS];
    #pragma unroll
    for (int r = 0; r < ROWS; ++r) { float2 q = p0[r]; px[r] = q.x; py[r] = q.y; }

    float bd[ROWS]; int bj[ROWS];
    #pragma unroll
    for (int r = 0; r < ROWS; ++r) { bd[r] = 3.0e38f; bj[r] = 0; }

    // stage-ahead double buffer; j ascends per thread => first-occurrence
    // argmin within a thread; cross-thread ties broken in the reduce.
    #define STAGE(BUF, c) \
        for (int j = tid; j < CH4; j += 256) BUF[j] = p1[(c) * CH4 + j];

    #define COMPUTE(BUF, c) \
        for (int j4 = tid; j4 < CH4; j4 += 256) { \
            float4 q = BUF[j4]; \
            const int j0 = (c) * CH + 2 * j4; \
            _Pragma("unroll") \
            for (int r = 0; r < ROWS; ++r) { \
                float dx = px[r] - q.x, dy = py[r] - q.y; \
                float d2 = dx * dx + dy * dy; \
                if (d2 < bd[r]) { bd[r] = d2; bj[r] = j0; } \
                float ex = px[r] - q.z, ey = py[r] - q.w; \
                float e2 = ex * ex + ey * ey; \
                if (e2 < bd[r]) { bd[r] = e2; bj[r] = j0 + 1; } \
            } \
        }

    STAGE(sA, 0);
    __syncthreads();
    STAGE(sB, 1); COMPUTE(sA, 0);
    __syncthreads();
    STAGE(sA, 2); COMPUTE(sB, 1);
    __syncthreads();
    STAGE(sB, 3); COMPUTE(sA, 2);
    __syncthreads();
    COMPUTE(sB, 3);
    #undef STAGE
    #undef COMPUTE

    // wave-level min+argmin, tie-break smaller j (first occurrence)
    #pragma unroll
    for (int r = 0; r < ROWS; ++r) {
        float d = bd[r]; int jj = bj[r];
        #pragma unroll
        for (int off = 32; off; off >>= 1) {
            float od = __shfl_xor(d, off);
            int   oj = __shfl_xor(jj, off);
            if (od < d || (od == d && oj < jj)) { d = od; jj = oj; }
        }
        if (lane == 0) { redd[r * 4 + wv] = d; redj[r * 4 + wv] = jj; }
    }
    __syncthreads();

    // parallel epilogue: lane r (< 8) handles row r; all loads overlap across
    // lanes. Query point is RELOADED from global (L1-hot) -- do NOT index
    // px[tid] (runtime index would demote the array to scratch everywhere).
    if (tid < ROWS) {
        const int r = tid;
        float d = redd[r * 4 + 0]; int jj = redj[r * 4 + 0];
        #pragma unroll
        for (int w = 1; w < 4; ++w) {
            float od = redd[r * 4 + w]; int oj = redj[r * 4 + w];
            if (od < d || (od == d && oj < jj)) { d = od; jj = oj; }
        }
        const float2 q0 = p0[r];
        const float l2 = sqrtf(d);
        const int gi = n * L0 + i0 + r;

        const float thr = 8.0f * scale0[n * 2 + 0];
        const float W1  = (float)W1C * scale1[n * 2 + 0];
        const float H1  = (float)H1C * scale1[n * 2 + 1];
        const float sxd = (W1 * 8.0f - 1.0f) * 0.5f;
        const float syd = (H1 * 8.0f - 1.0f) * 0.5f;
        const float* im = score1 + (size_t)n * L1;

        // both mask interpretations (int32 and float32 agree on word != 0)
        const float mw = (((const unsigned int*)maskp)[gi] != 0u) ? 1.0f : 0.0f;
        const float mb = (((const unsigned char*)maskp)[gi] != 0) ? 1.0f : 0.0f;
        const float inthr = (l2 <= thr) ? 1.0f : 0.0f;

        const float s0   = score0[gi];
        const float ssum = im[jj] + s0;

        // bilinear grid-sample of score1 as 60x80 image, zeros outside
        const float gx = (q0.x / sxd) * 0.5f * (float)(W1C - 1);
        const float gy = (q0.y / syd) * 0.5f * (float)(H1C - 1);
        const float x0 = floorf(gx), y0 = floorf(gy);
        const float x1 = x0 + 1.0f,  y1 = y0 + 1.0f;
        const float wx1 = gx - x0, wx0 = 1.0f - wx1;
        const float wy1 = gy - y0, wy0 = 1.0f - wy1;

        auto corner = [&](float xf, float yf) -> float {
            bool inb = (xf >= 0.0f) && (xf <= (float)(W1C - 1)) &&
                       (yf >= 0.0f) && (yf <= (float)(H1C - 1));
            int xc = (int)fminf(fmaxf(xf, 0.0f), (float)(W1C - 1));
            int yc = (int)fminf(fmaxf(yf, 0.0f), (float)(H1C - 1));
            float v = im[yc * W1C + xc];
            return inb ? v : 0.0f;
        };
        const float res = corner(x0, y0) * wx0 * wy0
                        + corner(x1, y0) * wx1 * wy0
                        + corner(x0, y1) * wx0 * wy1
                        + corner(x1, y1) * wx1 * wy1;
        const float dsc = res - s0;
        const float dsq = dsc * dsc;

        const float dvw = inthr * mw, dvb = inthr * mb;
        float v[12];
        v[0] = dvw;  v[1] = l2 * dvw;  v[2] = ssum * l2 * dvw;
        v[3] = ssum * dvw;  v[4] = mw;  v[5] = dsq * mw;
        v[6] = dvb;  v[7] = l2 * dvb;  v[8] = ssum * l2 * dvb;
        v[9] = ssum * dvb;  v[10] = mb; v[11] = dsq * mb;
        #pragma unroll
        for (int k = 0; k < 12; ++k) {
            float s = v[k];
            s += __shfl_xor(s, 4); s += __shfl_xor(s, 2); s += __shfl_xor(s, 1);
            v[k] = s;
        }
        if (tid == 0) {
            #pragma unroll
            for (int k = 0; k < 12; ++k) partials[k * NBLK + blk] = v[k];
        }
    }

    // last-block-done finalize (device-scope release/acquire)
    if (tid == 0) {
        __threadfence();
        unsigned int old = atomicAdd(counter, 1u);
        slast = (old == (unsigned int)(NBLK - 1)) ? 1 : 0;
    }
    __syncthreads();
    if (slast) {
        __threadfence();
        if (tid == 0) sbad = 0u;
        __syncthreads();
        // mask format detection: first 2400 words are in-bounds for every layout
        unsigned int bad = 0u;
        const unsigned int* mwp = (const unsigned int*)maskp;
        for (int i = tid; i < 2400; i += 256) {
            unsigned int w = mwp[i];
            if (w != 0u && w != 1u && w != 0x3f800000u) bad = 1u;
        }
        atomicOr(&sbad, bad);
        __syncthreads();
        const int off0 = (sbad == 0u) ? 0 : 6;   // word-format vs byte-format set

        for (int k = 0; k < 6; ++k) {
            float s = 0.0f;
            for (int rbl = tid; rbl < NBLK; rbl += 256)
                s += partials[(off0 + k) * NBLK + rbl];
            #pragma unroll
            for (int off = 32; off; off >>= 1) s += __shfl_xor(s, off);
            if (lane == 0) fin[k * 4 + wv] = s;
        }
        __syncthreads();
        if (tid == 0) {
            float S[6];
            #pragma unroll
            for (int k = 0; k < 6; ++k)
                S[k] = fin[k * 4 + 0] + fin[k * 4 + 1] + fin[k * 4 + 2] + fin[k * 4 + 3];
            const float den = fmaxf(S[0], 1.0f);
            const float lm  = S[1] / den;
            out[0] = lm;                          // loc_loss_mean
            out[1] = (S[2] - lm * S[3]) / den;    // rep_loss_mean
            out[2] = 2.0f * S[5] / fmaxf(S[4], 1.0f); // score_loss
        }
    }
}

extern "C" void kernel_launch(void* const* d_in, const int* in_sizes, int n_in,
                              void* d_out, int out_size, void* d_ws, size_t ws_size,
                              hipStream_t stream) {
    const float* w_pt0  = (const float*)d_in[0];
    const float* pt1    = (const float*)d_in[1];
    const void*  maskp  =               d_in[2];
    const float* score0 = (const float*)d_in[3];
    const float* score1 = (const float*)d_in[4];
    // d_in[5] = image1 (zeros) -- unused
    const float* scale0 = (const float*)d_in[6];
    const float* scale1 = (const float*)d_in[7];

    unsigned int* counter  = (unsigned int*)d_ws;
    float*        partials = (float*)((char*)d_ws + 256);

    hipMemsetAsync(d_ws, 0, 4, stream);   // zero the completion counter each call
    s2ld_fused<<<NBLK, 256, 0, stream>>>(w_pt0, pt1, maskp, score0, score1,
                                         scale0, scale1, partials, counter,
                                         (float*)d_out);
}

// Round 4
// 61.568 us; speedup vs baseline: 1.0470x; 1.0470x over previous
//
#include <hip/hip_runtime.h>
#include <math.h>

#define NB   2
#define L0   4800
#define L1   4800
#define H1C  60
#define W1C  80
#define ROWS 8
#define RPB  (L0 / ROWS)          // 600 row-groups per batch
#define NBLK (NB * RPB)           // 1200 blocks
#define L14  (L1 / 2)             // 2400 float4 per batch (2 points each)
// partials layout: k in [0,12): {Sm,Sl2,Ssl2,Ss,Sv,Ssq} x {word-mask, byte-mask}

__global__ __launch_bounds__(256) void s2ld_fused(
    const float* __restrict__ w_pt0,    // [NB][L0][2]
    const float* __restrict__ pt1,      // [NB][L1][2]
    const void*  __restrict__ maskp,    // [NB][L0], format unknown (word or byte)
    const float* __restrict__ score0,   // [NB][L0]
    const float* __restrict__ score1,   // [NB][L1]
    const float* __restrict__ scale0,   // [NB][2]
    const float* __restrict__ scale1,   // [NB][2]
    float*       __restrict__ partials, // [12][NBLK]
    unsigned int* __restrict__ counter,
    float*       __restrict__ out)      // [3]
{
    __shared__ float redd[ROWS * 4];
    __shared__ int   redj[ROWS * 4];
    __shared__ float fin[6 * 4];
    __shared__ int   slast;
    __shared__ unsigned int sbad;

    const int tid  = threadIdx.x;
    const int blk  = blockIdx.x;
    const int n    = blk / RPB;
    const int i0   = (blk % RPB) * ROWS;
    const int lane = tid & 63;
    const int wv   = tid >> 6;

    const float4* p1 = (const float4*)(pt1 + (size_t)n * L1 * 2);  // 2400/batch
    const float2* p0 = (const float2*)(w_pt0 + ((size_t)n * L0 + i0) * 2);

    // NAMED SCALARS ONLY in the hot loop -- no arrays, so no possible demotion
    // to scratch (rounds 2/3 spilled: VGPR=24 < the 32 live state words).
    float px0, px1, px2, px3, px4, px5, px6, px7;
    float py0, py1, py2, py3, py4, py5, py6, py7;
    {
        float2 q;
        q = p0[0]; px0 = q.x; py0 = q.y;
        q = p0[1]; px1 = q.x; py1 = q.y;
        q = p0[2]; px2 = q.x; py2 = q.y;
        q = p0[3]; px3 = q.x; py3 = q.y;
        q = p0[4]; px4 = q.x; py4 = q.y;
        q = p0[5]; px5 = q.x; py5 = q.y;
        q = p0[6]; px6 = q.x; py6 = q.y;
        q = p0[7]; px7 = q.x; py7 = q.y;
    }
    float bd0 = 3.0e38f, bd1 = 3.0e38f, bd2 = 3.0e38f, bd3 = 3.0e38f,
          bd4 = 3.0e38f, bd5 = 3.0e38f, bd6 = 3.0e38f, bd7 = 3.0e38f;
    int   bj0 = 0, bj1 = 0, bj2 = 0, bj3 = 0,
          bj4 = 0, bj5 = 0, bj6 = 0, bj7 = 0;

    // stream pt1 straight from L2 (38.4 KB/batch, fully cache-resident);
    // j ascends per thread => first-occurrence argmin within a thread.
#define DO_ROW(R) {                                                   \
        float dx = px##R - q.x, dy = py##R - q.y;                     \
        float dA = dx * dx + dy * dy;                                 \
        if (dA < bd##R) { bd##R = dA; bj##R = j0; }                   \
        float ex = px##R - q.z, ey = py##R - q.w;                     \
        float dB = ex * ex + ey * ey;                                 \
        if (dB < bd##R) { bd##R = dB; bj##R = j0 + 1; } }

    for (int j4 = tid; j4 < L14; j4 += 256) {
        const float4 q = p1[j4];
        const int j0 = 2 * j4;
        DO_ROW(0) DO_ROW(1) DO_ROW(2) DO_ROW(3)
        DO_ROW(4) DO_ROW(5) DO_ROW(6) DO_ROW(7)
    }
#undef DO_ROW

    // wave-level min+argmin, tie-break smaller j (first occurrence)
#define REDUCE_ROW(R) {                                               \
        float d = bd##R; int jj = bj##R;                              \
        for (int off = 32; off; off >>= 1) {                          \
            float od = __shfl_xor(d, off);                            \
            int   oj = __shfl_xor(jj, off);                           \
            if (od < d || (od == d && oj < jj)) { d = od; jj = oj; }  \
        }                                                             \
        if (lane == 0) { redd[R * 4 + wv] = d; redj[R * 4 + wv] = jj; } }

    REDUCE_ROW(0) REDUCE_ROW(1) REDUCE_ROW(2) REDUCE_ROW(3)
    REDUCE_ROW(4) REDUCE_ROW(5) REDUCE_ROW(6) REDUCE_ROW(7)
#undef REDUCE_ROW
    __syncthreads();

    // parallel epilogue: lane r (< 8) handles row r; loads overlap across
    // lanes; query point reloaded from global (L1-hot), no array indexing.
    if (tid < ROWS) {
        const int r = tid;
        float d = redd[r * 4 + 0]; int jj = redj[r * 4 + 0];
        #pragma unroll
        for (int w = 1; w < 4; ++w) {
            float od = redd[r * 4 + w]; int oj = redj[r * 4 + w];
            if (od < d || (od == d && oj < jj)) { d = od; jj = oj; }
        }
        const float2 q0 = p0[r];
        const float l2 = sqrtf(d);
        const int gi = n * L0 + i0 + r;

        const float thr = 8.0f * scale0[n * 2 + 0];
        const float W1  = (float)W1C * scale1[n * 2 + 0];
        const float H1  = (float)H1C * scale1[n * 2 + 1];
        const float sxd = (W1 * 8.0f - 1.0f) * 0.5f;
        const float syd = (H1 * 8.0f - 1.0f) * 0.5f;
        const float* im = score1 + (size_t)n * L1;

        // both mask interpretations (int32 and float32 agree on word != 0)
        const float mw = (((const unsigned int*)maskp)[gi] != 0u) ? 1.0f : 0.0f;
        const float mb = (((const unsigned char*)maskp)[gi] != 0) ? 1.0f : 0.0f;
        const float inthr = (l2 <= thr) ? 1.0f : 0.0f;

        const float s0   = score0[gi];
        const float ssum = im[jj] + s0;

        // bilinear grid-sample of score1 as 60x80 image, zeros outside
        const float gx = (q0.x / sxd) * 0.5f * (float)(W1C - 1);
        const float gy = (q0.y / syd) * 0.5f * (float)(H1C - 1);
        const float x0 = floorf(gx), y0 = floorf(gy);
        const float x1 = x0 + 1.0f,  y1 = y0 + 1.0f;
        const float wx1 = gx - x0, wx0 = 1.0f - wx1;
        const float wy1 = gy - y0, wy0 = 1.0f - wy1;

        auto corner = [&](float xf, float yf) -> float {
            bool inb = (xf >= 0.0f) && (xf <= (float)(W1C - 1)) &&
                       (yf >= 0.0f) && (yf <= (float)(H1C - 1));
            int xc = (int)fminf(fmaxf(xf, 0.0f), (float)(W1C - 1));
            int yc = (int)fminf(fmaxf(yf, 0.0f), (float)(H1C - 1));
            float v = im[yc * W1C + xc];
            return inb ? v : 0.0f;
        };
        const float res = corner(x0, y0) * wx0 * wy0
                        + corner(x1, y0) * wx1 * wy0
                        + corner(x0, y1) * wx0 * wy1
                        + corner(x1, y1) * wx1 * wy1;
        const float dsc = res - s0;
        const float dsq = dsc * dsc;

        const float dvw = inthr * mw, dvb = inthr * mb;
        float v0  = dvw,        v1 = l2 * dvw,  v2  = ssum * l2 * dvw;
        float v3  = ssum * dvw, v4 = mw,        v5  = dsq * mw;
        float v6  = dvb,        v7 = l2 * dvb,  v8  = ssum * l2 * dvb;
        float v9  = ssum * dvb, v10 = mb,       v11 = dsq * mb;
#define RED8(V) { V += __shfl_xor(V, 4); V += __shfl_xor(V, 2); V += __shfl_xor(V, 1); }
        RED8(v0) RED8(v1) RED8(v2) RED8(v3) RED8(v4)  RED8(v5)
        RED8(v6) RED8(v7) RED8(v8) RED8(v9) RED8(v10) RED8(v11)
#undef RED8
        if (tid == 0) {
            partials[ 0 * NBLK + blk] = v0;  partials[ 1 * NBLK + blk] = v1;
            partials[ 2 * NBLK + blk] = v2;  partials[ 3 * NBLK + blk] = v3;
            partials[ 4 * NBLK + blk] = v4;  partials[ 5 * NBLK + blk] = v5;
            partials[ 6 * NBLK + blk] = v6;  partials[ 7 * NBLK + blk] = v7;
            partials[ 8 * NBLK + blk] = v8;  partials[ 9 * NBLK + blk] = v9;
            partials[10 * NBLK + blk] = v10; partials[11 * NBLK + blk] = v11;
        }
    }

    // last-block-done finalize (device-scope release/acquire)
    if (tid == 0) {
        __threadfence();
        unsigned int old = atomicAdd(counter, 1u);
        slast = (old == (unsigned int)(NBLK - 1)) ? 1 : 0;
    }
    __syncthreads();
    if (slast) {
        __threadfence();
        if (tid == 0) sbad = 0u;
        __syncthreads();
        // mask format detection: first 2400 words in-bounds for every layout
        unsigned int bad = 0u;
        const unsigned int* mwp = (const unsigned int*)maskp;
        for (int i = tid; i < 2400; i += 256) {
            unsigned int w = mwp[i];
            if (w != 0u && w != 1u && w != 0x3f800000u) bad = 1u;
        }
        atomicOr(&sbad, bad);
        __syncthreads();
        const int off0 = (sbad == 0u) ? 0 : 6;   // word-format vs byte-format

        for (int k = 0; k < 6; ++k) {
            float s = 0.0f;
            for (int rbl = tid; rbl < NBLK; rbl += 256)
                s += partials[(off0 + k) * NBLK + rbl];
            #pragma unroll
            for (int off = 32; off; off >>= 1) s += __shfl_xor(s, off);
            if (lane == 0) fin[k * 4 + wv] = s;
        }
        __syncthreads();
        if (tid == 0) {
            float S0 = fin[0] + fin[1] + fin[2] + fin[3];
            float S1 = fin[4] + fin[5] + fin[6] + fin[7];
            float S2 = fin[8] + fin[9] + fin[10] + fin[11];
            float S3 = fin[12] + fin[13] + fin[14] + fin[15];
            float S4 = fin[16] + fin[17] + fin[18] + fin[19];
            float S5 = fin[20] + fin[21] + fin[22] + fin[23];
            const float den = fmaxf(S0, 1.0f);
            const float lm  = S1 / den;
            out[0] = lm;                              // loc_loss_mean
            out[1] = (S2 - lm * S3) / den;            // rep_loss_mean
            out[2] = 2.0f * S5 / fmaxf(S4, 1.0f);     // score_loss
        }
    }
}

extern "C" void kernel_launch(void* const* d_in, const int* in_sizes, int n_in,
                              void* d_out, int out_size, void* d_ws, size_t ws_size,
                              hipStream_t stream) {
    const float* w_pt0  = (const float*)d_in[0];
    const float* pt1    = (const float*)d_in[1];
    const void*  maskp  =               d_in[2];
    const float* score0 = (const float*)d_in[3];
    const float* score1 = (const float*)d_in[4];
    // d_in[5] = image1 (zeros) -- unused
    const float* scale0 = (const float*)d_in[6];
    const float* scale1 = (const float*)d_in[7];

    unsigned int* counter  = (unsigned int*)d_ws;
    float*        partials = (float*)((char*)d_ws + 256);

    hipMemsetAsync(d_ws, 0, 4, stream);   // zero the completion counter each call
    s2ld_fused<<<NBLK, 256, 0, stream>>>(w_pt0, pt1, maskp, score0, score1,
                                         scale0, scale1, partials, counter,
                                         (float*)d_out);
}